// Round 5
// baseline (523.143 us; speedup 1.0000x reference)
//
#include <hip/hip_runtime.h>
#include <hip/hip_bf16.h>
#include <hip/hip_cooperative_groups.h>

namespace cg = cooperative_groups;

#define C 2048
#define NODE 1024
#define H 8

typedef unsigned short u16;
typedef __attribute__((ext_vector_type(8))) short short8;
typedef __attribute__((ext_vector_type(4))) float f32x4;
typedef __attribute__((ext_vector_type(4))) unsigned short u16x4;
typedef __attribute__((ext_vector_type(8))) unsigned short u16x8;

static __device__ __forceinline__ float wave_reduce_sum(float v) {
  #pragma unroll
  for (int off = 32; off; off >>= 1) v += __shfl_down(v, off, 64);
  return v;
}
static __device__ __forceinline__ float wave_reduce_max(float v) {
  #pragma unroll
  for (int off = 32; off; off >>= 1) v = fmaxf(v, __shfl_down(v, off, 64));
  return v;
}
static __device__ __forceinline__ u16 f2bf(float x) {
  __hip_bfloat16 h = __float2bfloat16(x);
  return *reinterpret_cast<u16*>(&h);
}
static __device__ __forceinline__ float bf2f(u16 u) {
  unsigned v = ((unsigned)u) << 16;
  return __uint_as_float(v);
}

#define GLOAD_LDS16(g, l)                                                     \
  __builtin_amdgcn_global_load_lds(                                           \
      (const __attribute__((address_space(1))) void*)(g),                     \
      (__attribute__((address_space(3))) void*)(l), 16, 0, 0)

__global__ void k_zero(float* __restrict__ p) {
  p[blockIdx.x * 256 + threadIdx.x] = 0.f;
}

// obs_mean[i] = relu(Wo1[i,:] + bo1) . Wo2 + bo2   (one wave per row)
__global__ void k_obsmean(const float* __restrict__ Wo1, const float* __restrict__ bo1,
                          const float* __restrict__ Wo2, const float* __restrict__ bo2,
                          float* __restrict__ obs_mean) {
  int row = blockIdx.x * 4 + (threadIdx.x >> 6);
  int lane = threadIdx.x & 63;
  const float* wr = Wo1 + (size_t)row * NODE;
  float acc = 0.f;
  for (int n = lane; n < NODE; n += 64)
    acc += fmaxf(wr[n] + bo1[n], 0.f) * Wo2[n];
  acc = wave_reduce_sum(acc);
  if (lane == 0) obs_mean[row] = acc + bo2[0];
}

// elementwise fp32 -> bf16 for Wb1 rows [0,2048)
__global__ void k_cvt_wb1(const float* __restrict__ Wb1, u16* __restrict__ Wb1b) {
  size_t idx = ((size_t)blockIdx.x * 256 + threadIdx.x) * 4;
  const float4 v = *(const float4*)&Wb1[idx];
  u16x4 o;
  o.x = f2bf(v.x); o.y = f2bf(v.y); o.z = f2bf(v.z); o.w = f2bf(v.w);
  *(u16x4*)&Wb1b[idx] = o;
}

// transpose+convert: out[j][k] = bf16(in[k][j]), in is NODE x C
__global__ void k_cvt_wt2t(const float* __restrict__ Win, u16* __restrict__ outT) {
  __shared__ float sm[32][33];
  int tx = threadIdx.x & 31, ty = threadIdx.x >> 5;   // 32 x 8
  int jb = blockIdx.x * 32, kb = blockIdx.y * 32;
  #pragma unroll
  for (int r = 0; r < 4; ++r)
    sm[ty + r * 8][tx] = Win[(size_t)(kb + ty + r * 8) * C + jb + tx];
  __syncthreads();
  #pragma unroll
  for (int r = 0; r < 4; ++r)
    outT[(size_t)(jb + ty + r * 8) * NODE + kb + tx] = f2bf(sm[tx][ty + r * 8]);
}

// ---- persistent cooperative belief chain: 1 launch, 64 blocks, grid.sync ----
// Per step: phase A (redundant softmax -> sbel slice; split-K hidden partials)
//           phase B (redundant hidden finalize; 32 logit cols per block)
__global__ __launch_bounds__(256) void k_chain(
    const float* __restrict__ bel0,
    const u16* __restrict__ Wb1b, const float* __restrict__ Wb1,
    const float* __restrict__ bb1,
    const u16* __restrict__ Wb2t, const float* __restrict__ bb2,
    const float* __restrict__ actions, const float* __restrict__ obs,
    float* __restrict__ beliefs, float* __restrict__ hpart,
    float* __restrict__ logits_ch) {
  cg::grid_group grid = cg::this_grid();
  __shared__ float sl[C];
  __shared__ float sbel[64];
  __shared__ float red[4], redz[4];
  __shared__ float sh[NODE];
  __shared__ float sred[256];
  int b = blockIdx.x, t = threadIdx.x, w = t >> 6, lane = t & 63;
  int nc = b >> 5, kc = b & 31;

  for (int s = 0; s < H; ++s) {
    // ---- phase A ----
    if (s == 0) {
      if (t < 64) sbel[t] = bel0[kc * 64 + t];
      __syncthreads();
    } else {
      const float* lp = logits_ch + (size_t)s * C;
      #pragma unroll
      for (int i = 0; i < 8; ++i) sl[t + i * 256] = lp[t + i * 256];
      __syncthreads();
      float m = -3.4e38f;
      #pragma unroll
      for (int i = 0; i < 8; ++i) m = fmaxf(m, sl[t + i * 256]);
      m = wave_reduce_max(m);
      if (lane == 0) red[w] = m;
      __syncthreads();
      m = fmaxf(fmaxf(red[0], red[1]), fmaxf(red[2], red[3]));
      float z = 0.f;
      #pragma unroll
      for (int i = 0; i < 8; ++i) z += expf(sl[t + i * 256] - m);
      z = wave_reduce_sum(z);
      if (lane == 0) redz[w] = z;
      __syncthreads();
      float invz = 1.f / (redz[0] + redz[1] + redz[2] + redz[3]);
      if (t < 64) {
        float bl = expf(sl[kc * 64 + t] - m) * invz;
        sbel[t] = bl;
        if (nc == 0) beliefs[(size_t)s * C + kc * 64 + t] = bl;
      }
      __syncthreads();
    }
    {
      int n0 = nc * 512 + 2 * t;
      const u16* wp = Wb1b + (size_t)(kc * 64) * NODE + n0;
      float ax = 0.f, ay = 0.f;
      #pragma unroll 8
      for (int r = 0; r < 64; ++r) {
        float bl = sbel[r];
        unsigned pair = *(const unsigned*)&wp[(size_t)r * NODE];
        ax = fmaf(bl, bf2f((u16)(pair & 0xffff)), ax);
        ay = fmaf(bl, bf2f((u16)(pair >> 16)), ay);
      }
      hpart[(size_t)kc * NODE + n0] = ax;
      hpart[(size_t)kc * NODE + n0 + 1] = ay;
    }
    grid.sync();
    // ---- phase B ----
    {
      float a_s = actions[s], o_s = obs[s];
      #pragma unroll
      for (int i = 0; i < 4; ++i) {
        int n = t + i * 256;
        float h = bb1[n];
        #pragma unroll 8
        for (int kk = 0; kk < 32; ++kk) h += hpart[(size_t)kk * NODE + n];
        h = fmaf(a_s, Wb1[(size_t)C * NODE + n], h);
        h = fmaf(o_s, Wb1[(size_t)(C + 1) * NODE + n], h);
        sh[n] = fmaxf(h, 0.f);
      }
      __syncthreads();
      int j = b * 32 + (t >> 3);
      int ks = (t & 7) * 128;
      const u16* wp = Wb2t + (size_t)j * NODE + ks;
      float acc = 0.f;
      #pragma unroll
      for (int kk = 0; kk < 128; kk += 8) {
        u16x8 wv = *(const u16x8*)&wp[kk];
        #pragma unroll
        for (int q = 0; q < 8; ++q) acc = fmaf(sh[ks + kk + q], bf2f(wv[q]), acc);
      }
      sred[t] = acc;
      __syncthreads();
      if (t < 32) {
        float a = 0.f;
        #pragma unroll
        for (int p = 0; p < 8; ++p) a += sred[t * 8 + p];
        logits_ch[(size_t)(s + 1) * C + b * 32 + t] = a + bb2[b * 32 + t];
      }
      __syncthreads();
    }
    grid.sync();
  }
  // ---- final softmax of logits_ch[H] -> beliefs[H] (block 0 writes) ----
  {
    const float* lp = logits_ch + (size_t)H * C;
    float m = -3.4e38f;
    for (int j = t; j < C; j += 256) m = fmaxf(m, lp[j]);
    m = wave_reduce_max(m);
    if (lane == 0) red[w] = m;
    __syncthreads();
    m = fmaxf(fmaxf(red[0], red[1]), fmaxf(red[2], red[3]));
    float z = 0.f;
    for (int j = t; j < C; j += 256) z += expf(lp[j] - m);
    z = wave_reduce_sum(z);
    if (lane == 0) redz[w] = z;
    __syncthreads();
    z = redz[0] + redz[1] + redz[2] + redz[3];
    float inv = 1.f / z;
    if (b == 0)
      for (int j = t; j < C; j += 256)
        beliefs[(size_t)H * C + j] = expf(lp[j] - m) * inv;
  }
}

// hiddenb[s][i][n] = bf16(relu(Wt1[i][n] + a_s*Wt1[C][n] + bt1[n])) — one pass over Wt1
__global__ void k_cvt_hidden(const float* __restrict__ Wt1, const float* __restrict__ bt1,
                             const float* __restrict__ actions, u16* __restrict__ hiddenb) {
  int i = blockIdx.x;
  int n = threadIdx.x * 4;
  const float4 wv = *(const float4*)&Wt1[(size_t)i * NODE + n];
  const float4 wa = *(const float4*)&Wt1[(size_t)C * NODE + n];
  const float4 bv = *(const float4*)&bt1[n];
  #pragma unroll
  for (int s = 0; s < H; ++s) {
    float a_s = actions[s];
    u16x4 o;
    o.x = f2bf(fmaxf(fmaf(a_s, wa.x, wv.x) + bv.x, 0.f));
    o.y = f2bf(fmaxf(fmaf(a_s, wa.y, wv.y) + bv.y, 0.f));
    o.z = f2bf(fmaxf(fmaf(a_s, wa.z, wv.z) + bv.z, 0.f));
    o.w = f2bf(fmaxf(fmaf(a_s, wa.w, wv.w) + bv.w, 0.f));
    *(u16x4*)&hiddenb[((size_t)s * C + i) * NODE + n] = o;
  }
}

// ---- MFMA GEMM (BK=32) with XCD row-band swizzle.
// Writes E = bf16(exp(logit+bias)); row sums of E -> rowZ via atomics.
__global__ __launch_bounds__(256) void k_trans_gemm(
    const u16* __restrict__ Ab, const u16* __restrict__ Bt,
    const float* __restrict__ bt2, int s0,
    u16* __restrict__ outE, float* __restrict__ rowZ) {
  __shared__ u16 As[128 * 32];   // [row][k], 64 B rows
  __shared__ u16 Bs[128 * 32];   // [n][k]
  int tid = threadIdx.x;
  int lane = tid & 63;
  int w = tid >> 6;
  int quad = lane >> 4;
  int l16 = lane & 15;
  // XCD swizzle: lin%8 = XCD (round-robin dispatch). Each XCD owns a band of
  // gridDim.y/8 row tiles (A band ~2MB stays L2-hot) and walks col tiles.
  int lin = blockIdx.x + gridDim.x * blockIdx.y;
  int band = gridDim.y >> 3;
  int xcd = lin & 7;
  int jj = lin >> 3;
  int rt_ = xcd * band + (jj % band);
  int ct_ = jj / band;
  int r0 = rt_ * 128;            // group-local row
  int c0 = ct_ * 128;
  int wr = (w >> 1) * 64;
  int wc = (w & 1) * 64;

  f32x4 acc[4][4] = {};

  const u16* Ag = Ab + (size_t)(r0 + w * 32 + (lane >> 2)) * NODE + (lane & 3) * 8;
  const u16* Bg = Bt + (size_t)(c0 + w * 32 + (lane >> 2)) * NODE + (lane & 3) * 8;
  u16* AsW = &As[(w * 32) * 32];
  u16* BsW = &Bs[(w * 32) * 32];

  for (int k0 = 0; k0 < NODE; k0 += 32) {
    GLOAD_LDS16(Ag + k0, AsW);
    GLOAD_LDS16(Ag + (size_t)16 * NODE + k0, AsW + 16 * 32);
    GLOAD_LDS16(Bg + k0, BsW);
    GLOAD_LDS16(Bg + (size_t)16 * NODE + k0, BsW + 16 * 32);
    __syncthreads();
    short8 af[4], bfr[4];
    #pragma unroll
    for (int rt = 0; rt < 4; ++rt)
      af[rt] = *(const short8*)&As[(wr + rt * 16 + l16) * 32 + quad * 8];
    #pragma unroll
    for (int ct = 0; ct < 4; ++ct)
      bfr[ct] = *(const short8*)&Bs[(wc + ct * 16 + l16) * 32 + quad * 8];
    #pragma unroll
    for (int rt = 0; rt < 4; ++rt)
      #pragma unroll
      for (int ct = 0; ct < 4; ++ct)
        acc[rt][ct] = __builtin_amdgcn_mfma_f32_16x16x32_bf16(af[rt], bfr[ct], acc[rt][ct], 0, 0, 0);
    __syncthreads();
  }

  float bias[4];
  #pragma unroll
  for (int ct = 0; ct < 4; ++ct) bias[ct] = bt2[c0 + wc + ct * 16 + l16];
  #pragma unroll
  for (int rt = 0; rt < 4; ++rt) {
    #pragma unroll
    for (int rg = 0; rg < 4; ++rg) {
      int row = r0 + wr + rt * 16 + quad * 4 + rg;
      float rsum = 0.f;
      #pragma unroll
      for (int ct = 0; ct < 4; ++ct) {
        float e = __expf(acc[rt][ct][rg] + bias[ct]);
        u16 v = f2bf(e);
        outE[(size_t)row * C + c0 + wc + ct * 16 + l16] = v;
        rsum += bf2f(v);   // Z from rounded values -> pred exactly normalized
      }
      #pragma unroll
      for (int m = 1; m < 16; m <<= 1) rsum += __shfl_xor(rsum, m, 64);
      if (l16 == 0)
        atomicAdd(&rowZ[(size_t)(s0 + (row >> 11)) * C + (row & (C - 1))], rsum);
    }
  }
}

// partial pred over a 256-row chunk: pure bf16 FMA (no exp)
__global__ void k_pred_partial(const u16* __restrict__ E, const float* __restrict__ beliefs,
                               const float* __restrict__ rowZ, int s0,
                               float* __restrict__ partial) {
  int t = threadIdx.x;
  int sl = blockIdx.z;
  int s = s0 + sl;
  int j = blockIdx.x * 512 + 2 * t;
  int i0 = blockIdx.y * 256;
  __shared__ float sw_[256];
  sw_[t] = beliefs[(size_t)s * C + i0 + t] / rowZ[(size_t)s * C + i0 + t];
  __syncthreads();
  const u16* lp = E + ((size_t)sl * C + i0) * C + j;
  float ax = 0.f, ay = 0.f;
  #pragma unroll 8
  for (int ii = 0; ii < 256; ++ii) {
    unsigned pair = *(const unsigned*)&lp[(size_t)ii * C];
    float wv = sw_[ii];
    ax = fmaf(wv, bf2f((u16)(pair & 0xffff)), ax);
    ay = fmaf(wv, bf2f((u16)(pair >> 16)), ay);
  }
  size_t base = ((size_t)s * 8 + blockIdx.y) * C + j;
  partial[base] = ax;
  partial[base + 1] = ay;
}

// per step: first = -sum_j b*logp ; second = sum_j b*(log b - log pred); pred reduced inline
__global__ void k_loss(const float* __restrict__ beliefs, const float* __restrict__ partial,
                       const float* __restrict__ obs_mean, const float* __restrict__ obs,
                       float* __restrict__ loss_out) {
  int s = blockIdx.x, t = threadIdx.x;
  float o = obs[s];
  float f = 0.f, sec = 0.f;
  for (int j = t; j < C; j += 256) {
    float b = beliefs[(size_t)(s + 1) * C + j];
    float d = o - obs_mean[j];
    float logp = -0.5f * d * d - 0.91893853320467274178f;
    f -= b * logp;
    float p = 0.f;
    #pragma unroll
    for (int it = 0; it < 8; ++it) p += partial[((size_t)s * 8 + it) * C + j];
    sec += (b > 0.f) ? b * (logf(b) - logf(p)) : 0.f;
  }
  __shared__ float rf[4], rs[4];
  int w = t >> 6, lane = t & 63;
  f = wave_reduce_sum(f);
  sec = wave_reduce_sum(sec);
  if (lane == 0) { rf[w] = f; rs[w] = sec; }
  __syncthreads();
  if (t == 0) {
    loss_out[s] = rf[0] + rf[1] + rf[2] + rf[3];
    loss_out[H + s] = rs[0] + rs[1] + rs[2] + rs[3];
  }
}

__global__ void k_final(const float* __restrict__ loss_out, const float* __restrict__ beliefs,
                        float* __restrict__ out) {
  int t = threadIdx.x;
  if (t == 0) {
    float tot = 0.f;
    for (int s = 0; s < H; ++s) tot += loss_out[s] + loss_out[H + s];
    out[0] = tot;
  }
  for (int j = t; j < C; j += 256) out[1 + j] = beliefs[(size_t)H * C + j];
}

extern "C" void kernel_launch(void* const* d_in, const int* in_sizes, int n_in,
                              void* d_out, int out_size, void* d_ws, size_t ws_size,
                              hipStream_t stream) {
  const float* obs         = (const float*)d_in[0];
  const float* actions     = (const float*)d_in[1];
  const float* prev_belief = (const float*)d_in[2];
  const float* Wb1 = (const float*)d_in[3];
  const float* bb1 = (const float*)d_in[4];
  const float* Wb2 = (const float*)d_in[5];
  const float* bb2 = (const float*)d_in[6];
  const float* Wt1 = (const float*)d_in[7];
  const float* bt1 = (const float*)d_in[8];
  const float* Wt2 = (const float*)d_in[9];
  const float* bt2 = (const float*)d_in[10];
  const float* Wo1 = (const float*)d_in[11];
  const float* bo1 = (const float*)d_in[12];
  const float* Wo2 = (const float*)d_in[13];
  const float* bo2 = (const float*)d_in[14];
  float* out = (float*)d_out;

  char* base = (char*)d_ws;
  size_t off = 0;
  auto alloc = [&](size_t bytes) {
    char* r = base + off;
    off = (off + bytes + 255) & ~(size_t)255;
    return r;
  };
  float* obs_mean   = (float*)alloc((size_t)C * 4);
  float* beliefs    = (float*)alloc((size_t)(H + 1) * C * 4);
  float* hpart      = (float*)alloc((size_t)32 * NODE * 4);
  float* logits_ch  = (float*)alloc((size_t)(H + 1) * C * 4);
  float* rowZ       = (float*)alloc((size_t)H * C * 4);
  float* partial    = (float*)alloc((size_t)H * 8 * C * 4);
  float* lossbuf    = (float*)alloc(64 * 4);
  u16* hiddenb      = (u16*)alloc((size_t)H * C * NODE * 2);
  u16* wt2t         = (u16*)alloc((size_t)C * NODE * 2);
  u16* Wb1b         = (u16*)alloc((size_t)C * NODE * 2);
  u16* Wb2t         = (u16*)alloc((size_t)C * NODE * 2);
  u16* E_bf         = (u16*)(base + off);
  size_t rem = (ws_size > off) ? ws_size - off : 0;
  int g = (int)(rem / ((size_t)C * C * 2));
  if (g < 1) g = 1;
  if (g > H) g = H;

  k_obsmean<<<dim3(C / 4), 256, 0, stream>>>(Wo1, bo1, Wo2, bo2, obs_mean);
  hipMemcpyAsync(beliefs, prev_belief, (size_t)C * sizeof(float),
                 hipMemcpyDeviceToDevice, stream);
  k_zero<<<dim3(H * C / 256), 256, 0, stream>>>(rowZ);
  k_cvt_wt2t<<<dim3(C / 32, NODE / 32), 256, 0, stream>>>(Wt2, wt2t);
  k_cvt_wt2t<<<dim3(C / 32, NODE / 32), 256, 0, stream>>>(Wb2, Wb2t);
  k_cvt_wb1<<<dim3((C * NODE) / 1024), 256, 0, stream>>>(Wb1, Wb1b);
  k_cvt_hidden<<<dim3(C), 256, 0, stream>>>(Wt1, bt1, actions, hiddenb);

  {
    const float* a0 = prev_belief;
    const u16* a1 = Wb1b;  const float* a2 = Wb1;  const float* a3 = bb1;
    const u16* a4 = Wb2t;  const float* a5 = bb2;
    const float* a6 = actions; const float* a7 = obs;
    float* a8 = beliefs; float* a9 = hpart; float* a10 = logits_ch;
    void* args[] = { (void*)&a0, (void*)&a1, (void*)&a2, (void*)&a3, (void*)&a4,
                     (void*)&a5, (void*)&a6, (void*)&a7, (void*)&a8, (void*)&a9,
                     (void*)&a10 };
    hipLaunchCooperativeKernel((void*)k_chain, dim3(64), dim3(256), args, 0, stream);
  }

  for (int s0 = 0; s0 < H; s0 += g) {
    int gg = (H - s0 < g) ? (H - s0) : g;
    k_trans_gemm<<<dim3(C / 128, gg * (C / 128)), 256, 0, stream>>>(
        hiddenb + (size_t)s0 * C * NODE, wt2t, bt2, s0, E_bf, rowZ);
    k_pred_partial<<<dim3(C / 512, C / 256, gg), 256, 0, stream>>>(E_bf, beliefs, rowZ, s0,
                                                                   partial);
  }
  k_loss<<<dim3(H), 256, 0, stream>>>(beliefs, partial, obs_mean, obs, lossbuf);
  k_final<<<1, 256, 0, stream>>>(lossbuf, beliefs, out);
}

// Round 6
// 375.451 us; speedup vs baseline: 1.3934x; 1.3934x over previous
//
#include <hip/hip_runtime.h>
#include <hip/hip_bf16.h>

#define C 2048
#define NODE 1024
#define H 8

typedef unsigned short u16;
typedef __attribute__((ext_vector_type(8))) short short8;
typedef __attribute__((ext_vector_type(4))) float f32x4;
typedef __attribute__((ext_vector_type(4))) unsigned short u16x4;
typedef __attribute__((ext_vector_type(8))) unsigned short u16x8;

static __device__ __forceinline__ float wave_reduce_sum(float v) {
  #pragma unroll
  for (int off = 32; off; off >>= 1) v += __shfl_down(v, off, 64);
  return v;
}
static __device__ __forceinline__ float wave_reduce_max(float v) {
  #pragma unroll
  for (int off = 32; off; off >>= 1) v = fmaxf(v, __shfl_down(v, off, 64));
  return v;
}
static __device__ __forceinline__ u16 f2bf(float x) {
  __hip_bfloat16 h = __float2bfloat16(x);
  return *reinterpret_cast<u16*>(&h);
}
static __device__ __forceinline__ float bf2f(u16 u) {
  unsigned v = ((unsigned)u) << 16;
  return __uint_as_float(v);
}

#define GLOAD_LDS16(g, l)                                                     \
  __builtin_amdgcn_global_load_lds(                                           \
      (const __attribute__((address_space(1))) void*)(g),                     \
      (__attribute__((address_space(3))) void*)(l), 16, 0, 0)

__global__ void k_zero(float* __restrict__ p) {
  p[blockIdx.x * 256 + threadIdx.x] = 0.f;
}

// obs_mean[i] = relu(Wo1[i,:] + bo1) . Wo2 + bo2   (one wave per row)
__global__ void k_obsmean(const float* __restrict__ Wo1, const float* __restrict__ bo1,
                          const float* __restrict__ Wo2, const float* __restrict__ bo2,
                          float* __restrict__ obs_mean) {
  int row = blockIdx.x * 4 + (threadIdx.x >> 6);
  int lane = threadIdx.x & 63;
  const float* wr = Wo1 + (size_t)row * NODE;
  float acc = 0.f;
  for (int n = lane; n < NODE; n += 64)
    acc += fmaxf(wr[n] + bo1[n], 0.f) * Wo2[n];
  acc = wave_reduce_sum(acc);
  if (lane == 0) obs_mean[row] = acc + bo2[0];
}

// elementwise fp32 -> bf16 for Wb1 rows [0,2048)
__global__ void k_cvt_wb1(const float* __restrict__ Wb1, u16* __restrict__ Wb1b) {
  size_t idx = ((size_t)blockIdx.x * 256 + threadIdx.x) * 4;
  const float4 v = *(const float4*)&Wb1[idx];
  u16x4 o;
  o.x = f2bf(v.x); o.y = f2bf(v.y); o.z = f2bf(v.z); o.w = f2bf(v.w);
  *(u16x4*)&Wb1b[idx] = o;
}

// transpose+convert: out[j][k] = bf16(in[k][j]), in is NODE x C
__global__ void k_cvt_wt2t(const float* __restrict__ Win, u16* __restrict__ outT) {
  __shared__ float sm[32][33];
  int tx = threadIdx.x & 31, ty = threadIdx.x >> 5;   // 32 x 8
  int jb = blockIdx.x * 32, kb = blockIdx.y * 32;
  #pragma unroll
  for (int r = 0; r < 4; ++r)
    sm[ty + r * 8][tx] = Win[(size_t)(kb + ty + r * 8) * C + jb + tx];
  __syncthreads();
  #pragma unroll
  for (int r = 0; r < 4; ++r)
    outT[(size_t)(jb + ty + r * 8) * NODE + kb + tx] = f2bf(sm[tx][ty + r * 8]);
}

// ---- belief chain: 2 kernels/step (round-4 dispatch version — coop launch was
// 2.5x slower: 17 grid.syncs cost ~14us each on 8 XCDs) ----
__global__ void k_bel_hidden(const float* __restrict__ logits_prev,
                             const float* __restrict__ bel0, int first,
                             const u16* __restrict__ Wb1b,
                             float* __restrict__ bel_out, float* __restrict__ hpart) {
  __shared__ float sl[C];
  __shared__ float sbel[64];
  __shared__ float red[4], redz[4];
  int t = threadIdx.x, w = t >> 6, lane = t & 63;
  int nc = blockIdx.x, kc = blockIdx.y;
  if (first) {
    if (t < 64) sbel[t] = bel0[kc * 64 + t];
    __syncthreads();
  } else {
    #pragma unroll
    for (int i = 0; i < 8; ++i) sl[t + i * 256] = logits_prev[t + i * 256];
    __syncthreads();
    float m = -3.4e38f;
    #pragma unroll
    for (int i = 0; i < 8; ++i) m = fmaxf(m, sl[t + i * 256]);
    m = wave_reduce_max(m);
    if (lane == 0) red[w] = m;
    __syncthreads();
    m = fmaxf(fmaxf(red[0], red[1]), fmaxf(red[2], red[3]));
    float z = 0.f;
    #pragma unroll
    for (int i = 0; i < 8; ++i) z += expf(sl[t + i * 256] - m);
    z = wave_reduce_sum(z);
    if (lane == 0) redz[w] = z;
    __syncthreads();
    float invz = 1.f / (redz[0] + redz[1] + redz[2] + redz[3]);
    if (t < 64) {
      float b = expf(sl[kc * 64 + t] - m) * invz;
      sbel[t] = b;
      if (nc == 0) bel_out[kc * 64 + t] = b;
    }
    __syncthreads();
  }
  int n0 = nc * 512 + 2 * t;
  const u16* wp = Wb1b + (size_t)(kc * 64) * NODE + n0;
  float ax = 0.f, ay = 0.f;
  #pragma unroll 8
  for (int r = 0; r < 64; ++r) {
    float b = sbel[r];
    unsigned pair = *(const unsigned*)&wp[(size_t)r * NODE];
    ax = fmaf(b, bf2f((u16)(pair & 0xffff)), ax);
    ay = fmaf(b, bf2f((u16)(pair >> 16)), ay);
  }
  hpart[(size_t)kc * NODE + n0] = ax;
  hpart[(size_t)kc * NODE + n0 + 1] = ay;
}

__global__ void k_bel_logits(const float* __restrict__ hpart, const float* __restrict__ Wb1,
                             const float* __restrict__ bb1,
                             const float* __restrict__ actions, const float* __restrict__ obs,
                             int s, const u16* __restrict__ Wb2t, const float* __restrict__ bb2,
                             float* __restrict__ logits_out) {
  __shared__ float sh[NODE];
  __shared__ float sred[256];
  int t = threadIdx.x;
  int jc = blockIdx.x;
  float a_s = actions[s], o_s = obs[s];
  #pragma unroll
  for (int i = 0; i < 4; ++i) {
    int n = t + i * 256;
    float h = bb1[n];
    #pragma unroll 8
    for (int kc = 0; kc < 32; ++kc) h += hpart[(size_t)kc * NODE + n];
    h = fmaf(a_s, Wb1[(size_t)C * NODE + n], h);
    h = fmaf(o_s, Wb1[(size_t)(C + 1) * NODE + n], h);
    sh[n] = fmaxf(h, 0.f);
  }
  __syncthreads();
  int j = jc * 32 + (t >> 3);
  int ks = (t & 7) * 128;
  const u16* wp = Wb2t + (size_t)j * NODE + ks;
  float acc = 0.f;
  #pragma unroll
  for (int kk = 0; kk < 128; kk += 8) {
    u16x8 wv = *(const u16x8*)&wp[kk];
    #pragma unroll
    for (int q = 0; q < 8; ++q) acc = fmaf(sh[ks + kk + q], bf2f(wv[q]), acc);
  }
  sred[t] = acc;
  __syncthreads();
  if (t < 32) {
    float a = 0.f;
    #pragma unroll
    for (int p = 0; p < 8; ++p) a += sred[t * 8 + p];
    logits_out[jc * 32 + t] = a + bb2[jc * 32 + t];
  }
}

__global__ void k_softmax_final(const float* __restrict__ logits, float* __restrict__ belief) {
  __shared__ float red[4], redz[4];
  int t = threadIdx.x, w = t >> 6, lane = t & 63;
  float m = -3.4e38f;
  for (int j = t; j < C; j += 256) m = fmaxf(m, logits[j]);
  m = wave_reduce_max(m);
  if (lane == 0) red[w] = m;
  __syncthreads();
  m = fmaxf(fmaxf(red[0], red[1]), fmaxf(red[2], red[3]));
  float z = 0.f;
  for (int j = t; j < C; j += 256) z += expf(logits[j] - m);
  z = wave_reduce_sum(z);
  if (lane == 0) redz[w] = z;
  __syncthreads();
  z = redz[0] + redz[1] + redz[2] + redz[3];
  float inv = 1.f / z;
  for (int j = t; j < C; j += 256) belief[j] = expf(logits[j] - m) * inv;
}

// hiddenb[s][i][n] = bf16(relu(Wt1[i][n] + a_s*Wt1[C][n] + bt1[n])) — one pass over Wt1
__global__ void k_cvt_hidden(const float* __restrict__ Wt1, const float* __restrict__ bt1,
                             const float* __restrict__ actions, u16* __restrict__ hiddenb) {
  int i = blockIdx.x;
  int n = threadIdx.x * 4;
  const float4 wv = *(const float4*)&Wt1[(size_t)i * NODE + n];
  const float4 wa = *(const float4*)&Wt1[(size_t)C * NODE + n];
  const float4 bv = *(const float4*)&bt1[n];
  #pragma unroll
  for (int s = 0; s < H; ++s) {
    float a_s = actions[s];
    u16x4 o;
    o.x = f2bf(fmaxf(fmaf(a_s, wa.x, wv.x) + bv.x, 0.f));
    o.y = f2bf(fmaxf(fmaf(a_s, wa.y, wv.y) + bv.y, 0.f));
    o.z = f2bf(fmaxf(fmaf(a_s, wa.z, wv.z) + bv.z, 0.f));
    o.w = f2bf(fmaxf(fmaf(a_s, wa.w, wv.w) + bv.w, 0.f));
    *(u16x4*)&hiddenb[((size_t)s * C + i) * NODE + n] = o;
  }
}

// ---- MFMA GEMM: 256x256 tile, 512 threads (8 waves, each 64x128), BK=32.
// 32 MFMA per wave per barrier (2x the 128-tile version), 1 block/CU.
// Writes E = bf16(exp(logit+bias)); row sums of E -> rowZ via atomics.
__global__ __launch_bounds__(512, 2) void k_trans_gemm(
    const u16* __restrict__ Ab, const u16* __restrict__ Bt,
    const float* __restrict__ bt2, int s0,
    u16* __restrict__ outE, float* __restrict__ rowZ) {
  __shared__ u16 As[256 * 32];   // [row][k], 64 B rows, 16 KB
  __shared__ u16 Bs[256 * 32];   // [n][k], 16 KB
  int tid = threadIdx.x;
  int lane = tid & 63;
  int w = tid >> 6;              // 0..7
  int quad = lane >> 4;
  int l16 = lane & 15;
  // XCD band swizzle: lin%8 = XCD; each XCD owns a contiguous row band.
  int lin = blockIdx.x + gridDim.x * blockIdx.y;  // gridDim.x = 8 col tiles
  int band = gridDim.y >> 3;
  int xcd = lin & 7;
  int jj = lin >> 3;
  int r0 = (xcd * band + (jj % band)) * 256;      // group-local row
  int c0 = (jj / band) * 256;
  int wr = (w >> 1) * 64;        // 4 wave-rows
  int wc = (w & 1) * 128;        // 2 wave-cols

  f32x4 acc[4][8] = {};

  const u16* Ag = Ab + (size_t)(r0 + w * 32 + (lane >> 2)) * NODE + (lane & 3) * 8;
  const u16* Bg = Bt + (size_t)(c0 + w * 32 + (lane >> 2)) * NODE + (lane & 3) * 8;
  u16* AsW = &As[(w * 32) * 32];
  u16* BsW = &Bs[(w * 32) * 32];

  for (int k0 = 0; k0 < NODE; k0 += 32) {
    GLOAD_LDS16(Ag + k0, AsW);
    GLOAD_LDS16(Ag + (size_t)16 * NODE + k0, AsW + 16 * 32);
    GLOAD_LDS16(Bg + k0, BsW);
    GLOAD_LDS16(Bg + (size_t)16 * NODE + k0, BsW + 16 * 32);
    __syncthreads();
    short8 af[4], bfr[8];
    #pragma unroll
    for (int rt = 0; rt < 4; ++rt)
      af[rt] = *(const short8*)&As[(wr + rt * 16 + l16) * 32 + quad * 8];
    #pragma unroll
    for (int ct = 0; ct < 8; ++ct)
      bfr[ct] = *(const short8*)&Bs[(wc + ct * 16 + l16) * 32 + quad * 8];
    #pragma unroll
    for (int rt = 0; rt < 4; ++rt)
      #pragma unroll
      for (int ct = 0; ct < 8; ++ct)
        acc[rt][ct] = __builtin_amdgcn_mfma_f32_16x16x32_bf16(af[rt], bfr[ct], acc[rt][ct], 0, 0, 0);
    __syncthreads();
  }

  float bias[8];
  #pragma unroll
  for (int ct = 0; ct < 8; ++ct) bias[ct] = bt2[c0 + wc + ct * 16 + l16];
  #pragma unroll
  for (int rt = 0; rt < 4; ++rt) {
    #pragma unroll
    for (int rg = 0; rg < 4; ++rg) {
      int row = r0 + wr + rt * 16 + quad * 4 + rg;
      float rsum = 0.f;
      #pragma unroll
      for (int ct = 0; ct < 8; ++ct) {
        float e = __expf(acc[rt][ct][rg] + bias[ct]);
        u16 v = f2bf(e);
        outE[(size_t)row * C + c0 + wc + ct * 16 + l16] = v;
        rsum += bf2f(v);   // Z from rounded values -> pred exactly normalized
      }
      #pragma unroll
      for (int m = 1; m < 16; m <<= 1) rsum += __shfl_xor(rsum, m, 64);
      if (l16 == 0)
        atomicAdd(&rowZ[(size_t)(s0 + (row >> 11)) * C + (row & (C - 1))], rsum);
    }
  }
}

// partial pred over a 256-row chunk: pure bf16 FMA (no exp)
__global__ void k_pred_partial(const u16* __restrict__ E, const float* __restrict__ beliefs,
                               const float* __restrict__ rowZ, int s0,
                               float* __restrict__ partial) {
  int t = threadIdx.x;
  int sl = blockIdx.z;
  int s = s0 + sl;
  int j = blockIdx.x * 512 + 2 * t;
  int i0 = blockIdx.y * 256;
  __shared__ float sw_[256];
  sw_[t] = beliefs[(size_t)s * C + i0 + t] / rowZ[(size_t)s * C + i0 + t];
  __syncthreads();
  const u16* lp = E + ((size_t)sl * C + i0) * C + j;
  float ax = 0.f, ay = 0.f;
  #pragma unroll 8
  for (int ii = 0; ii < 256; ++ii) {
    unsigned pair = *(const unsigned*)&lp[(size_t)ii * C];
    float wv = sw_[ii];
    ax = fmaf(wv, bf2f((u16)(pair & 0xffff)), ax);
    ay = fmaf(wv, bf2f((u16)(pair >> 16)), ay);
  }
  size_t base = ((size_t)s * 8 + blockIdx.y) * C + j;
  partial[base] = ax;
  partial[base + 1] = ay;
}

// per step: first = -sum_j b*logp ; second = sum_j b*(log b - log pred); pred reduced inline
__global__ void k_loss(const float* __restrict__ beliefs, const float* __restrict__ partial,
                       const float* __restrict__ obs_mean, const float* __restrict__ obs,
                       float* __restrict__ loss_out) {
  int s = blockIdx.x, t = threadIdx.x;
  float o = obs[s];
  float f = 0.f, sec = 0.f;
  for (int j = t; j < C; j += 256) {
    float b = beliefs[(size_t)(s + 1) * C + j];
    float d = o - obs_mean[j];
    float logp = -0.5f * d * d - 0.91893853320467274178f;
    f -= b * logp;
    float p = 0.f;
    #pragma unroll
    for (int it = 0; it < 8; ++it) p += partial[((size_t)s * 8 + it) * C + j];
    sec += (b > 0.f) ? b * (logf(b) - logf(p)) : 0.f;
  }
  __shared__ float rf[4], rs[4];
  int w = t >> 6, lane = t & 63;
  f = wave_reduce_sum(f);
  sec = wave_reduce_sum(sec);
  if (lane == 0) { rf[w] = f; rs[w] = sec; }
  __syncthreads();
  if (t == 0) {
    loss_out[s] = rf[0] + rf[1] + rf[2] + rf[3];
    loss_out[H + s] = rs[0] + rs[1] + rs[2] + rs[3];
  }
}

__global__ void k_final(const float* __restrict__ loss_out, const float* __restrict__ beliefs,
                        float* __restrict__ out) {
  int t = threadIdx.x;
  if (t == 0) {
    float tot = 0.f;
    for (int s = 0; s < H; ++s) tot += loss_out[s] + loss_out[H + s];
    out[0] = tot;
  }
  for (int j = t; j < C; j += 256) out[1 + j] = beliefs[(size_t)H * C + j];
}

extern "C" void kernel_launch(void* const* d_in, const int* in_sizes, int n_in,
                              void* d_out, int out_size, void* d_ws, size_t ws_size,
                              hipStream_t stream) {
  const float* obs         = (const float*)d_in[0];
  const float* actions     = (const float*)d_in[1];
  const float* prev_belief = (const float*)d_in[2];
  const float* Wb1 = (const float*)d_in[3];
  const float* bb1 = (const float*)d_in[4];
  const float* Wb2 = (const float*)d_in[5];
  const float* bb2 = (const float*)d_in[6];
  const float* Wt1 = (const float*)d_in[7];
  const float* bt1 = (const float*)d_in[8];
  const float* Wt2 = (const float*)d_in[9];
  const float* bt2 = (const float*)d_in[10];
  const float* Wo1 = (const float*)d_in[11];
  const float* bo1 = (const float*)d_in[12];
  const float* Wo2 = (const float*)d_in[13];
  const float* bo2 = (const float*)d_in[14];
  float* out = (float*)d_out;

  char* base = (char*)d_ws;
  size_t off = 0;
  auto alloc = [&](size_t bytes) {
    char* r = base + off;
    off = (off + bytes + 255) & ~(size_t)255;
    return r;
  };
  float* obs_mean   = (float*)alloc((size_t)C * 4);
  float* beliefs    = (float*)alloc((size_t)(H + 1) * C * 4);
  float* hpart      = (float*)alloc((size_t)32 * NODE * 4);
  float* logits_ch  = (float*)alloc((size_t)(H + 1) * C * 4);
  float* rowZ       = (float*)alloc((size_t)H * C * 4);
  float* partial    = (float*)alloc((size_t)H * 8 * C * 4);
  float* lossbuf    = (float*)alloc(64 * 4);
  u16* hiddenb      = (u16*)alloc((size_t)H * C * NODE * 2);
  u16* wt2t         = (u16*)alloc((size_t)C * NODE * 2);
  u16* Wb1b         = (u16*)alloc((size_t)C * NODE * 2);
  u16* Wb2t         = (u16*)alloc((size_t)C * NODE * 2);
  u16* E_bf         = (u16*)(base + off);
  size_t rem = (ws_size > off) ? ws_size - off : 0;
  int g = (int)(rem / ((size_t)C * C * 2));
  if (g < 1) g = 1;
  if (g > H) g = H;

  k_obsmean<<<dim3(C / 4), 256, 0, stream>>>(Wo1, bo1, Wo2, bo2, obs_mean);
  hipMemcpyAsync(beliefs, prev_belief, (size_t)C * sizeof(float),
                 hipMemcpyDeviceToDevice, stream);
  k_zero<<<dim3(H * C / 256), 256, 0, stream>>>(rowZ);
  k_cvt_wt2t<<<dim3(C / 32, NODE / 32), 256, 0, stream>>>(Wt2, wt2t);
  k_cvt_wt2t<<<dim3(C / 32, NODE / 32), 256, 0, stream>>>(Wb2, Wb2t);
  k_cvt_wb1<<<dim3((C * NODE) / 1024), 256, 0, stream>>>(Wb1, Wb1b);
  k_cvt_hidden<<<dim3(C), 256, 0, stream>>>(Wt1, bt1, actions, hiddenb);

  for (int s = 0; s < H; ++s) {
    k_bel_hidden<<<dim3(2, 32), 256, 0, stream>>>(
        logits_ch + (size_t)s * C, beliefs, s == 0, Wb1b,
        beliefs + (size_t)s * C, hpart);
    k_bel_logits<<<dim3(64), 256, 0, stream>>>(hpart, Wb1, bb1, actions, obs, s,
                                               Wb2t, bb2, logits_ch + (size_t)(s + 1) * C);
  }
  k_softmax_final<<<1, 256, 0, stream>>>(logits_ch + (size_t)H * C, beliefs + (size_t)H * C);

  for (int s0 = 0; s0 < H; s0 += g) {
    int gg = (H - s0 < g) ? (H - s0) : g;
    k_trans_gemm<<<dim3(C / 256, gg * (C / 256)), 512, 0, stream>>>(
        hiddenb + (size_t)s0 * C * NODE, wt2t, bt2, s0, E_bf, rowZ);
    k_pred_partial<<<dim3(C / 512, C / 256, gg), 256, 0, stream>>>(E_bf, beliefs, rowZ, s0,
                                                                   partial);
  }
  k_loss<<<dim3(H), 256, 0, stream>>>(beliefs, partial, obs_mean, obs, lossbuf);
  k_final<<<1, 256, 0, stream>>>(lossbuf, beliefs, out);
}

// Round 7
// 365.941 us; speedup vs baseline: 1.4296x; 1.0260x over previous
//
#include <hip/hip_runtime.h>
#include <hip/hip_bf16.h>

#define C 2048
#define NODE 1024
#define H 8

typedef unsigned short u16;
typedef __attribute__((ext_vector_type(8))) short short8;
typedef __attribute__((ext_vector_type(4))) float f32x4;
typedef __attribute__((ext_vector_type(4))) unsigned short u16x4;
typedef __attribute__((ext_vector_type(8))) unsigned short u16x8;

static __device__ __forceinline__ float wave_reduce_sum(float v) {
  #pragma unroll
  for (int off = 32; off; off >>= 1) v += __shfl_down(v, off, 64);
  return v;
}
static __device__ __forceinline__ float wave_reduce_max(float v) {
  #pragma unroll
  for (int off = 32; off; off >>= 1) v = fmaxf(v, __shfl_down(v, off, 64));
  return v;
}
static __device__ __forceinline__ u16 f2bf(float x) {
  __hip_bfloat16 h = __float2bfloat16(x);
  return *reinterpret_cast<u16*>(&h);
}
static __device__ __forceinline__ float bf2f(u16 u) {
  unsigned v = ((unsigned)u) << 16;
  return __uint_as_float(v);
}

#define GLOAD_LDS16(g, l)                                                     \
  __builtin_amdgcn_global_load_lds(                                           \
      (const __attribute__((address_space(1))) void*)(g),                     \
      (__attribute__((address_space(3))) void*)(l), 16, 0, 0)

// Fused prep: blocks [0,512) obs_mean; [512,544) zero rowZ; 544 copy belief0.
__global__ void k_prep_misc(const float* __restrict__ Wo1, const float* __restrict__ bo1,
                            const float* __restrict__ Wo2, const float* __restrict__ bo2,
                            float* __restrict__ obs_mean,
                            float* __restrict__ rowZ,
                            const float* __restrict__ prev_belief,
                            float* __restrict__ beliefs) {
  int b = blockIdx.x, t = threadIdx.x;
  if (b < 512) {
    int row = b * 4 + (t >> 6);
    int lane = t & 63;
    const float* wr = Wo1 + (size_t)row * NODE;
    float acc = 0.f;
    for (int n = lane; n < NODE; n += 64)
      acc += fmaxf(wr[n] + bo1[n], 0.f) * Wo2[n];
    acc = wave_reduce_sum(acc);
    if (lane == 0) obs_mean[row] = acc + bo2[0];
  } else if (b < 544) {
    rowZ[(b - 512) * 256 + t] = 0.f;
  } else {
    #pragma unroll
    for (int i = 0; i < 8; ++i) beliefs[t + i * 256] = prev_belief[t + i * 256];
  }
}

// transpose+convert both Wt2 and Wb2 (z selects): out[j][k] = bf16(in[k][j])
__global__ void k_cvt_w2(const float* __restrict__ Wt2, u16* __restrict__ wt2t,
                         const float* __restrict__ Wb2, u16* __restrict__ Wb2t) {
  const float* Win = blockIdx.z ? Wb2 : Wt2;
  u16* outT = blockIdx.z ? Wb2t : wt2t;
  __shared__ float sm[32][33];
  int tx = threadIdx.x & 31, ty = threadIdx.x >> 5;   // 32 x 8
  int jb = blockIdx.x * 32, kb = blockIdx.y * 32;
  #pragma unroll
  for (int r = 0; r < 4; ++r)
    sm[ty + r * 8][tx] = Win[(size_t)(kb + ty + r * 8) * C + jb + tx];
  __syncthreads();
  #pragma unroll
  for (int r = 0; r < 4; ++r)
    outT[(size_t)(jb + ty + r * 8) * NODE + kb + tx] = f2bf(sm[tx][ty + r * 8]);
}

// blocks [0,C): hiddenb[s][i][:] for all s; blocks [C,2C): Wb1 -> bf16
__global__ void k_cvt_hidden_wb1(const float* __restrict__ Wt1, const float* __restrict__ bt1,
                                 const float* __restrict__ actions, u16* __restrict__ hiddenb,
                                 const float* __restrict__ Wb1, u16* __restrict__ Wb1b) {
  int b = blockIdx.x;
  if (b < C) {
    int n = threadIdx.x * 4;
    const float4 wv = *(const float4*)&Wt1[(size_t)b * NODE + n];
    const float4 wa = *(const float4*)&Wt1[(size_t)C * NODE + n];
    const float4 bv = *(const float4*)&bt1[n];
    #pragma unroll
    for (int s = 0; s < H; ++s) {
      float a_s = actions[s];
      u16x4 o;
      o.x = f2bf(fmaxf(fmaf(a_s, wa.x, wv.x) + bv.x, 0.f));
      o.y = f2bf(fmaxf(fmaf(a_s, wa.y, wv.y) + bv.y, 0.f));
      o.z = f2bf(fmaxf(fmaf(a_s, wa.z, wv.z) + bv.z, 0.f));
      o.w = f2bf(fmaxf(fmaf(a_s, wa.w, wv.w) + bv.w, 0.f));
      *(u16x4*)&hiddenb[((size_t)s * C + b) * NODE + n] = o;
    }
  } else {
    size_t idx = ((size_t)(b - C) * 256 + threadIdx.x) * 4;
    const float4 v = *(const float4*)&Wb1[idx];
    u16x4 o;
    o.x = f2bf(v.x); o.y = f2bf(v.y); o.z = f2bf(v.z); o.w = f2bf(v.w);
    *(u16x4*)&Wb1b[idx] = o;
  }
}

// ---- belief chain: 2 kernels/step ----
__global__ void k_bel_hidden(const float* __restrict__ logits_prev,
                             const float* __restrict__ bel0, int first,
                             const u16* __restrict__ Wb1b,
                             float* __restrict__ bel_out, float* __restrict__ hpart) {
  __shared__ float sl[C];
  __shared__ float sbel[64];
  __shared__ float red[4], redz[4];
  int t = threadIdx.x, w = t >> 6, lane = t & 63;
  int nc = blockIdx.x, kc = blockIdx.y;
  if (first) {
    if (t < 64) sbel[t] = bel0[kc * 64 + t];
    __syncthreads();
  } else {
    #pragma unroll
    for (int i = 0; i < 8; ++i) sl[t + i * 256] = logits_prev[t + i * 256];
    __syncthreads();
    float m = -3.4e38f;
    #pragma unroll
    for (int i = 0; i < 8; ++i) m = fmaxf(m, sl[t + i * 256]);
    m = wave_reduce_max(m);
    if (lane == 0) red[w] = m;
    __syncthreads();
    m = fmaxf(fmaxf(red[0], red[1]), fmaxf(red[2], red[3]));
    float z = 0.f;
    #pragma unroll
    for (int i = 0; i < 8; ++i) z += expf(sl[t + i * 256] - m);
    z = wave_reduce_sum(z);
    if (lane == 0) redz[w] = z;
    __syncthreads();
    float invz = 1.f / (redz[0] + redz[1] + redz[2] + redz[3]);
    if (t < 64) {
      float b = expf(sl[kc * 64 + t] - m) * invz;
      sbel[t] = b;
      if (nc == 0) bel_out[kc * 64 + t] = b;
    }
    __syncthreads();
  }
  int n0 = nc * 512 + 2 * t;
  const u16* wp = Wb1b + (size_t)(kc * 64) * NODE + n0;
  float ax = 0.f, ay = 0.f;
  #pragma unroll 8
  for (int r = 0; r < 64; ++r) {
    float b = sbel[r];
    unsigned pair = *(const unsigned*)&wp[(size_t)r * NODE];
    ax = fmaf(b, bf2f((u16)(pair & 0xffff)), ax);
    ay = fmaf(b, bf2f((u16)(pair >> 16)), ay);
  }
  hpart[(size_t)kc * NODE + n0] = ax;
  hpart[(size_t)kc * NODE + n0 + 1] = ay;
}

__global__ void k_bel_logits(const float* __restrict__ hpart, const float* __restrict__ Wb1,
                             const float* __restrict__ bb1,
                             const float* __restrict__ actions, const float* __restrict__ obs,
                             int s, const u16* __restrict__ Wb2t, const float* __restrict__ bb2,
                             float* __restrict__ logits_out) {
  __shared__ float sh[NODE];
  __shared__ float sred[256];
  int t = threadIdx.x;
  int jc = blockIdx.x;
  float a_s = actions[s], o_s = obs[s];
  #pragma unroll
  for (int i = 0; i < 4; ++i) {
    int n = t + i * 256;
    float h = bb1[n];
    #pragma unroll 8
    for (int kc = 0; kc < 32; ++kc) h += hpart[(size_t)kc * NODE + n];
    h = fmaf(a_s, Wb1[(size_t)C * NODE + n], h);
    h = fmaf(o_s, Wb1[(size_t)(C + 1) * NODE + n], h);
    sh[n] = fmaxf(h, 0.f);
  }
  __syncthreads();
  int j = jc * 32 + (t >> 3);
  int ks = (t & 7) * 128;
  const u16* wp = Wb2t + (size_t)j * NODE + ks;
  float acc = 0.f;
  #pragma unroll
  for (int kk = 0; kk < 128; kk += 8) {
    u16x8 wv = *(const u16x8*)&wp[kk];
    #pragma unroll
    for (int q = 0; q < 8; ++q) acc = fmaf(sh[ks + kk + q], bf2f(wv[q]), acc);
  }
  sred[t] = acc;
  __syncthreads();
  if (t < 32) {
    float a = 0.f;
    #pragma unroll
    for (int p = 0; p < 8; ++p) a += sred[t * 8 + p];
    logits_out[jc * 32 + t] = a + bb2[jc * 32 + t];
  }
}

__global__ void k_softmax_final(const float* __restrict__ logits, float* __restrict__ belief) {
  __shared__ float red[4], redz[4];
  int t = threadIdx.x, w = t >> 6, lane = t & 63;
  float m = -3.4e38f;
  for (int j = t; j < C; j += 256) m = fmaxf(m, logits[j]);
  m = wave_reduce_max(m);
  if (lane == 0) red[w] = m;
  __syncthreads();
  m = fmaxf(fmaxf(red[0], red[1]), fmaxf(red[2], red[3]));
  float z = 0.f;
  for (int j = t; j < C; j += 256) z += expf(logits[j] - m);
  z = wave_reduce_sum(z);
  if (lane == 0) redz[w] = z;
  __syncthreads();
  z = redz[0] + redz[1] + redz[2] + redz[3];
  float inv = 1.f / z;
  for (int j = t; j < C; j += 256) belief[j] = expf(logits[j] - m) * inv;
}

// ---- MFMA GEMM: 256x256 tile, 512 threads, BK=32, DOUBLE-BUFFERED LDS.
// 1 block/CU (VGPR-capped) so there is no inter-block overlap to hide the
// global->LDS drain; the explicit second buffer overlaps it with compute.
__global__ __launch_bounds__(512, 2) void k_trans_gemm(
    const u16* __restrict__ Ab, const u16* __restrict__ Bt,
    const float* __restrict__ bt2, int s0,
    u16* __restrict__ outE, float* __restrict__ rowZ) {
  __shared__ u16 As[2][256 * 32];   // 2 x 16 KB
  __shared__ u16 Bs[2][256 * 32];
  int tid = threadIdx.x;
  int lane = tid & 63;
  int w = tid >> 6;              // 0..7
  int quad = lane >> 4;
  int l16 = lane & 15;
  // XCD band swizzle: lin%8 = XCD; each XCD owns a contiguous row band,
  // walks row tiles innermost (B col-tile + A band stay L2-hot).
  int lin = blockIdx.x + gridDim.x * blockIdx.y;  // gridDim.x = 8 col tiles
  int band = gridDim.y >> 3;
  int xcd = lin & 7;
  int jj = lin >> 3;
  int r0 = (xcd * band + (jj % band)) * 256;      // group-local row
  int c0 = (jj / band) * 256;
  int wr = (w >> 1) * 64;        // 4 wave-rows
  int wc = (w & 1) * 128;        // 2 wave-cols

  f32x4 acc[4][8] = {};

  const u16* Ag = Ab + (size_t)(r0 + w * 32 + (lane >> 2)) * NODE + (lane & 3) * 8;
  const u16* Bg = Bt + (size_t)(c0 + w * 32 + (lane >> 2)) * NODE + (lane & 3) * 8;
  u16* AsW0 = &As[0][(w * 32) * 32];
  u16* BsW0 = &Bs[0][(w * 32) * 32];
  u16* AsW1 = &As[1][(w * 32) * 32];
  u16* BsW1 = &Bs[1][(w * 32) * 32];

#define STAGE(buf, koff)                                                      \
  do {                                                                        \
    GLOAD_LDS16(Ag + (koff), AsW##buf);                                       \
    GLOAD_LDS16(Ag + (koff) + (size_t)16 * NODE, AsW##buf + 16 * 32);         \
    GLOAD_LDS16(Bg + (koff), BsW##buf);                                       \
    GLOAD_LDS16(Bg + (koff) + (size_t)16 * NODE, BsW##buf + 16 * 32);         \
  } while (0)

#define COMPUTE(buf)                                                          \
  do {                                                                        \
    short8 af[4], bfr[8];                                                     \
    _Pragma("unroll")                                                         \
    for (int rt = 0; rt < 4; ++rt)                                            \
      af[rt] = *(const short8*)&As[buf][(wr + rt * 16 + l16) * 32 + quad * 8];\
    _Pragma("unroll")                                                         \
    for (int ct = 0; ct < 8; ++ct)                                            \
      bfr[ct] = *(const short8*)&Bs[buf][(wc + ct * 16 + l16) * 32 + quad * 8];\
    _Pragma("unroll")                                                         \
    for (int rt = 0; rt < 4; ++rt)                                            \
      _Pragma("unroll")                                                       \
      for (int ct = 0; ct < 8; ++ct)                                          \
        acc[rt][ct] = __builtin_amdgcn_mfma_f32_16x16x32_bf16(                \
            af[rt], bfr[ct], acc[rt][ct], 0, 0, 0);                           \
  } while (0)

  STAGE(0, 0);
  __syncthreads();
  for (int k0 = 0; k0 < NODE; k0 += 64) {
    STAGE(1, k0 + 32);        // prefetch next tile while computing current
    COMPUTE(0);
    __syncthreads();          // drains prefetch (overlapped with COMPUTE above)
    if (k0 + 64 < NODE) STAGE(0, k0 + 64);
    COMPUTE(1);
    __syncthreads();
  }
#undef STAGE
#undef COMPUTE

  float bias[8];
  #pragma unroll
  for (int ct = 0; ct < 8; ++ct) bias[ct] = bt2[c0 + wc + ct * 16 + l16];
  #pragma unroll
  for (int rt = 0; rt < 4; ++rt) {
    #pragma unroll
    for (int rg = 0; rg < 4; ++rg) {
      int row = r0 + wr + rt * 16 + quad * 4 + rg;
      float rsum = 0.f;
      #pragma unroll
      for (int ct = 0; ct < 8; ++ct) {
        float e = __expf(acc[rt][ct][rg] + bias[ct]);
        u16 v = f2bf(e);
        outE[(size_t)row * C + c0 + wc + ct * 16 + l16] = v;
        rsum += bf2f(v);   // Z from rounded values -> pred exactly normalized
      }
      #pragma unroll
      for (int m = 1; m < 16; m <<= 1) rsum += __shfl_xor(rsum, m, 64);
      if (l16 == 0)
        atomicAdd(&rowZ[(size_t)(s0 + (row >> 11)) * C + (row & (C - 1))], rsum);
    }
  }
}

// partial pred over a 256-row chunk: pure bf16 FMA (no exp)
__global__ void k_pred_partial(const u16* __restrict__ E, const float* __restrict__ beliefs,
                               const float* __restrict__ rowZ, int s0,
                               float* __restrict__ partial) {
  int t = threadIdx.x;
  int sl = blockIdx.z;
  int s = s0 + sl;
  int j = blockIdx.x * 512 + 2 * t;
  int i0 = blockIdx.y * 256;
  __shared__ float sw_[256];
  sw_[t] = beliefs[(size_t)s * C + i0 + t] / rowZ[(size_t)s * C + i0 + t];
  __syncthreads();
  const u16* lp = E + ((size_t)sl * C + i0) * C + j;
  float ax = 0.f, ay = 0.f;
  #pragma unroll 8
  for (int ii = 0; ii < 256; ++ii) {
    unsigned pair = *(const unsigned*)&lp[(size_t)ii * C];
    float wv = sw_[ii];
    ax = fmaf(wv, bf2f((u16)(pair & 0xffff)), ax);
    ay = fmaf(wv, bf2f((u16)(pair >> 16)), ay);
  }
  size_t base = ((size_t)s * 8 + blockIdx.y) * C + j;
  partial[base] = ax;
  partial[base + 1] = ay;
}

// per step: first = -sum_j b*logp ; second = sum_j b*(log b - log pred)
__global__ void k_loss(const float* __restrict__ beliefs, const float* __restrict__ partial,
                       const float* __restrict__ obs_mean, const float* __restrict__ obs,
                       float* __restrict__ loss_out) {
  int s = blockIdx.x, t = threadIdx.x;
  float o = obs[s];
  float f = 0.f, sec = 0.f;
  for (int j = t; j < C; j += 256) {
    float b = beliefs[(size_t)(s + 1) * C + j];
    float d = o - obs_mean[j];
    float logp = -0.5f * d * d - 0.91893853320467274178f;
    f -= b * logp;
    float p = 0.f;
    #pragma unroll
    for (int it = 0; it < 8; ++it) p += partial[((size_t)s * 8 + it) * C + j];
    sec += (b > 0.f) ? b * (logf(b) - logf(p)) : 0.f;
  }
  __shared__ float rf[4], rs[4];
  int w = t >> 6, lane = t & 63;
  f = wave_reduce_sum(f);
  sec = wave_reduce_sum(sec);
  if (lane == 0) { rf[w] = f; rs[w] = sec; }
  __syncthreads();
  if (t == 0) {
    loss_out[s] = rf[0] + rf[1] + rf[2] + rf[3];
    loss_out[H + s] = rs[0] + rs[1] + rs[2] + rs[3];
  }
}

__global__ void k_final(const float* __restrict__ loss_out, const float* __restrict__ beliefs,
                        float* __restrict__ out) {
  int t = threadIdx.x;
  if (t == 0) {
    float tot = 0.f;
    for (int s = 0; s < H; ++s) tot += loss_out[s] + loss_out[H + s];
    out[0] = tot;
  }
  for (int j = t; j < C; j += 256) out[1 + j] = beliefs[(size_t)H * C + j];
}

extern "C" void kernel_launch(void* const* d_in, const int* in_sizes, int n_in,
                              void* d_out, int out_size, void* d_ws, size_t ws_size,
                              hipStream_t stream) {
  const float* obs         = (const float*)d_in[0];
  const float* actions     = (const float*)d_in[1];
  const float* prev_belief = (const float*)d_in[2];
  const float* Wb1 = (const float*)d_in[3];
  const float* bb1 = (const float*)d_in[4];
  const float* Wb2 = (const float*)d_in[5];
  const float* bb2 = (const float*)d_in[6];
  const float* Wt1 = (const float*)d_in[7];
  const float* bt1 = (const float*)d_in[8];
  const float* Wt2 = (const float*)d_in[9];
  const float* bt2 = (const float*)d_in[10];
  const float* Wo1 = (const float*)d_in[11];
  const float* bo1 = (const float*)d_in[12];
  const float* Wo2 = (const float*)d_in[13];
  const float* bo2 = (const float*)d_in[14];
  float* out = (float*)d_out;

  char* base = (char*)d_ws;
  size_t off = 0;
  auto alloc = [&](size_t bytes) {
    char* r = base + off;
    off = (off + bytes + 255) & ~(size_t)255;
    return r;
  };
  float* obs_mean   = (float*)alloc((size_t)C * 4);
  float* beliefs    = (float*)alloc((size_t)(H + 1) * C * 4);
  float* hpart      = (float*)alloc((size_t)32 * NODE * 4);
  float* logits_ch  = (float*)alloc((size_t)(H + 1) * C * 4);
  float* rowZ       = (float*)alloc((size_t)H * C * 4);
  float* partial    = (float*)alloc((size_t)H * 8 * C * 4);
  float* lossbuf    = (float*)alloc(64 * 4);
  u16* hiddenb      = (u16*)alloc((size_t)H * C * NODE * 2);
  u16* wt2t         = (u16*)alloc((size_t)C * NODE * 2);
  u16* Wb1b         = (u16*)alloc((size_t)C * NODE * 2);
  u16* Wb2t         = (u16*)alloc((size_t)C * NODE * 2);
  u16* E_bf         = (u16*)(base + off);
  size_t rem = (ws_size > off) ? ws_size - off : 0;
  int g = (int)(rem / ((size_t)C * C * 2));
  if (g < 1) g = 1;
  if (g > H) g = H;

  k_prep_misc<<<dim3(545), 256, 0, stream>>>(Wo1, bo1, Wo2, bo2, obs_mean,
                                             rowZ, prev_belief, beliefs);
  k_cvt_w2<<<dim3(C / 32, NODE / 32, 2), 256, 0, stream>>>(Wt2, wt2t, Wb2, Wb2t);
  k_cvt_hidden_wb1<<<dim3(2 * C), 256, 0, stream>>>(Wt1, bt1, actions, hiddenb, Wb1, Wb1b);

  for (int s = 0; s < H; ++s) {
    k_bel_hidden<<<dim3(2, 32), 256, 0, stream>>>(
        logits_ch + (size_t)s * C, beliefs, s == 0, Wb1b,
        beliefs + (size_t)s * C, hpart);
    k_bel_logits<<<dim3(64), 256, 0, stream>>>(hpart, Wb1, bb1, actions, obs, s,
                                               Wb2t, bb2, logits_ch + (size_t)(s + 1) * C);
  }
  k_softmax_final<<<1, 256, 0, stream>>>(logits_ch + (size_t)H * C, beliefs + (size_t)H * C);

  for (int s0 = 0; s0 < H; s0 += g) {
    int gg = (H - s0 < g) ? (H - s0) : g;
    k_trans_gemm<<<dim3(C / 256, gg * (C / 256)), 512, 0, stream>>>(
        hiddenb + (size_t)s0 * C * NODE, wt2t, bt2, s0, E_bf, rowZ);
    k_pred_partial<<<dim3(C / 512, C / 256, gg), 256, 0, stream>>>(E_bf, beliefs, rowZ, s0,
                                                                   partial);
  }
  k_loss<<<dim3(H), 256, 0, stream>>>(beliefs, partial, obs_mean, obs, lossbuf);
  k_final<<<1, 256, 0, stream>>>(lossbuf, beliefs, out);
}